// Round 6
// baseline (1344.269 us; speedup 1.0000x reference)
//
#include <hip/hip_runtime.h>
#include <math.h>

#define C 96
#define K 512
#define P_PER_B 110592   // 48*48*48
#define NPOS 221184      // 2 * 110592
#define G 64             // prototypes per accumulator group
#define NG (K / G)       // 8 groups
#define CCH 8            // channels per chunk
// ---------------------------------------------------------------------------
// Strategy (validated round 3, absmax=0): harness reference is fp32 numpy.
// Fast FMA pass computes best/second + margin; margin < 1e-4*||x|| positions
// (~0.1%) are re-resolved with a bit-exact numpy-fp32 emulation.
//
// Round 6 restructure: rounds 3-5 proved the allocator will never keep 96
// remat-able x-loads resident (remat r3 / spill r4-r5). Invert the tiling:
// the register-resident state is now 64 loop-carried ACCUMULATORS (not
// remat-able, never profitably spilled); x streams through 8-channel chunks,
// re-read once per prototype group (8x re-read = 680 MB from L2, ~20 us,
// hidden by 13.5 waves/CU). Prototype reads stay wave-uniform -> s_load on
// the scalar pipe, overlapping FMA issue. Rolled outer loops keep the hot
// body ~6 KB (I$-safe). Issue floor 138 us.
// ---------------------------------------------------------------------------

// Workspace: pn[512][96] fp32, numpy-exact normalized prototypes (192 KB).

__global__ __launch_bounds__(256) void prep_kernel(const float* __restrict__ proto,
                                                   float* __restrict__ pn) {
    int k = blockIdx.x * 256 + threadIdx.x;
    if (k >= K) return;
    const float* row = proto + k * C;
    // numpy pairwise_sum, n=96 <= blocksize: 8 accumulators + fixed combine
    float r[8];
#pragma unroll
    for (int j = 0; j < 8; ++j) r[j] = __fmul_rn(row[j], row[j]);
    for (int i = 8; i < C; i += 8) {
#pragma unroll
        for (int j = 0; j < 8; ++j)
            r[j] = __fadd_rn(r[j], __fmul_rn(row[i + j], row[i + j]));
    }
    float res = __fadd_rn(__fadd_rn(__fadd_rn(r[0], r[1]), __fadd_rn(r[2], r[3])),
                          __fadd_rn(__fadd_rn(r[4], r[5]), __fadd_rn(r[6], r[7])));
    float n = fmaxf(__fsqrt_rn(res), 1e-12f);
    float* dst = pn + k * C;
    for (int c = 0; c < C; ++c) dst[c] = __fdiv_rn(row[c], n);
}

// ---------------------------------------------------------------------------
// Fast pass: accumulator-group argmax. One thread per position, 64-thread
// blocks (3456 blocks -> 13.5 waves/CU for latency hiding).
// ---------------------------------------------------------------------------
__global__ __launch_bounds__(64) void sim_argmax_kernel(
        const float* __restrict__ x,
        const float* __restrict__ pn,
        int* __restrict__ out) {
    int g = blockIdx.x * 64 + threadIdx.x;   // grid exact: g < NPOS
    int b = (g >= P_PER_B) ? 1 : 0;
    int p = g - b * P_PER_B;
    const float* xv = x + (size_t)b * (size_t)C * P_PER_B + p;

    float best = -3.4e38f, second = -3.4e38f;
    int bestk = 0;
    float n2 = 0.f;   // accumulates NG copies of ||x||^2 (scaled out in tau)

#pragma unroll 1
    for (int kg = 0; kg < K; kg += G) {
        const float* pg = pn + (size_t)kg * C;
        float acc[G];
#pragma unroll
        for (int kk = 0; kk < G; ++kk) acc[kk] = 0.f;

#pragma unroll 1
        for (int cc = 0; cc < C; cc += CCH) {
            float xc[CCH];
#pragma unroll
            for (int j = 0; j < CCH; ++j)
                xc[j] = xv[(size_t)(cc + j) * P_PER_B];   // coalesced across lanes
#pragma unroll
            for (int j = 0; j < CCH; ++j)
                n2 = fmaf(xc[j], xc[j], n2);
#pragma unroll
            for (int kk = 0; kk < G; ++kk) {
                const float* pr = pg + kk * C + cc;       // wave-uniform -> s_load
#pragma unroll
                for (int j = 0; j < CCH; ++j)
                    acc[kk] = fmaf(xc[j], pr[j], acc[kk]);
            }
        }

#pragma unroll
        for (int kk = 0; kk < G; ++kk) {
            float s = acc[kk];
            if (s > best) {
                second = best;
                best = s;
                bestk = kg + kk;
            } else if (s > second) {
                second = s;
            }
        }
    }

    // worst-case (fast-pass + numpy) rounding < 1.8e-5*||x||; 5x margin.
    // n2 counted each channel NG times -> scale by 1/NG.
    float tau = 1e-4f * sqrtf(n2 * (1.0f / NG));
    out[g] = (best - second < tau) ? (bestk | (int)0x80000000) : bestk;
}

// ---------------------------------------------------------------------------
// Refine pass (validated round 3): bit-exact numpy-fp32 emulation of flagged
// positions. Thread t handles prototypes t and t+256; LDS tree argmax with
// first-index tie-break.
// ---------------------------------------------------------------------------
__global__ __launch_bounds__(256) void refine_kernel(
        const float* __restrict__ x,
        const float* __restrict__ pn,
        int* __restrict__ out) {
    __shared__ int list[256];
    __shared__ int cnt;
    __shared__ float xn[C];
    __shared__ float nrm_s;
    __shared__ float sc[256];
    __shared__ int ki[256];

    int tid = threadIdx.x;
    int g = blockIdx.x * 256 + tid;

    if (tid == 0) cnt = 0;
    __syncthreads();

    if (out[g] < 0) {
        int i = atomicAdd(&cnt, 1);
        list[i] = g;
    }
    __syncthreads();
    int n = cnt;

    for (int i = 0; i < n; ++i) {
        int gg = list[i];
        int b = (gg >= P_PER_B) ? 1 : 0;
        int p = gg - b * P_PER_B;
        const float* xb = x + (size_t)b * (size_t)C * P_PER_B + p;

        if (tid < C) xn[tid] = xb[(size_t)tid * P_PER_B];
        __syncthreads();

        // numpy: norm over non-contiguous axis -> strictly sequential fp32
        if (tid == 0) {
            float acc = __fmul_rn(xn[0], xn[0]);
            for (int c = 1; c < C; ++c)
                acc = __fadd_rn(acc, __fmul_rn(xn[c], xn[c]));
            nrm_s = fmaxf(__fsqrt_rn(acc), 1e-12f);
        }
        __syncthreads();
        if (tid < C) xn[tid] = __fdiv_rn(xn[tid], nrm_s);
        __syncthreads();

        // einsum optimize=False: sequential fp32 mul+add, c ascending, no FMA
        const float* pr0 = pn + (size_t)tid * C;
        const float* pr1 = pn + (size_t)(tid + 256) * C;
        float s0 = 0.f, s1 = 0.f;
        for (int c = 0; c < C; ++c) {
            s0 = __fadd_rn(s0, __fmul_rn(xn[c], pr0[c]));
            s1 = __fadd_rn(s1, __fmul_rn(xn[c], pr1[c]));
        }

        float bv = s0;
        int bk = tid;
        if (s1 > bv) { bv = s1; bk = tid + 256; }  // strict: lower index wins ties

        sc[tid] = bv;
        ki[tid] = bk;
        __syncthreads();

        for (int off = 128; off > 0; off >>= 1) {
            if (tid < off) {
                float ov = sc[tid + off];
                int oi = ki[tid + off];
                if (ov > sc[tid] || (ov == sc[tid] && oi < ki[tid])) {
                    sc[tid] = ov;
                    ki[tid] = oi;
                }
            }
            __syncthreads();
        }

        if (tid == 0) out[gg] = ki[0];
        __syncthreads();
    }
}

// ---------------------------------------------------------------------------
extern "C" void kernel_launch(void* const* d_in, const int* in_sizes, int n_in,
                              void* d_out, int out_size, void* d_ws, size_t ws_size,
                              hipStream_t stream) {
    const float* x = (const float*)d_in[0];      // [2,96,48,48,48] fp32
    const float* proto = (const float*)d_in[1];  // [512,96] fp32
    int* out = (int*)d_out;                      // [2,48,48,48] int32

    float* pn = (float*)d_ws;                    // 512*96*4 = 196608 B

    prep_kernel<<<2, 256, 0, stream>>>(proto, pn);
    sim_argmax_kernel<<<NPOS / 64, 64, 0, stream>>>(x, pn, out);
    refine_kernel<<<NPOS / 256, 256, 0, stream>>>(x, pn, out);
}

// Round 7
// 427.229 us; speedup vs baseline: 3.1465x; 3.1465x over previous
//
#include <hip/hip_runtime.h>
#include <math.h>

#define C 96
#define K 512
#define P_PER_B 110592   // 48*48*48
#define NPOS 221184      // 2 * 110592
#define MT 64            // positions per block
#define NT 64            // prototypes per chunk

// ---------------------------------------------------------------------------
// Strategy (validated round 3, absmax=0): harness reference is fp32 numpy.
// Fast pass computes best/second + margin; margin < 1e-4*||x|| positions are
// re-resolved with a bit-exact numpy-fp32 emulation (refine_kernel).
//
// Round 7 restructure: rounds 3-6 proved the allocator refuses >~50 VGPRs of
// per-thread state here (remat r3 / spill r4,r5 / acc-spill r6). So: classic
// LDS-tiled GEMM with a 4x4 register micro-tile (state ~50 VGPR by design).
// x-tile [96][64] in LDS (staged once/block), pnT chunk [96][64] in LDS
// (staged per 64-proto chunk); per channel: 2x ds_read_b128 (24 cyc/wave)
// under 16 FMA (32 cyc/wave). LDS reads are broadcast/2-way -> conflict-free.
// Per-position top-2 merged across the 16 proto-owner threads in LDS.
// ---------------------------------------------------------------------------

// Workspace: pnT[96][512] fp32 = numpy-exact normalized prototypes,
// TRANSPOSED to channel-major (192 KB).

__global__ __launch_bounds__(256) void prep_kernel(const float* __restrict__ proto,
                                                   float* __restrict__ pnT) {
    int k = blockIdx.x * 256 + threadIdx.x;
    if (k >= K) return;
    const float* row = proto + k * C;
    // numpy pairwise_sum, n=96 <= blocksize: 8 accumulators + fixed combine
    float r[8];
#pragma unroll
    for (int j = 0; j < 8; ++j) r[j] = __fmul_rn(row[j], row[j]);
    for (int i = 8; i < C; i += 8) {
#pragma unroll
        for (int j = 0; j < 8; ++j)
            r[j] = __fadd_rn(r[j], __fmul_rn(row[i + j], row[i + j]));
    }
    float res = __fadd_rn(__fadd_rn(__fadd_rn(r[0], r[1]), __fadd_rn(r[2], r[3])),
                          __fadd_rn(__fadd_rn(r[4], r[5]), __fadd_rn(r[6], r[7])));
    float n = fmaxf(__fsqrt_rn(res), 1e-12f);
    for (int c = 0; c < C; ++c)
        pnT[(size_t)c * K + k] = __fdiv_rn(row[c], n);   // coalesced across k
}

// ---------------------------------------------------------------------------
// Fast pass: LDS-tiled argmax-GEMM. 256 threads: tm = tid&15 (position
// group), tn = tid>>4 (prototype group); thread tile = 4 pos x 4 protos.
// ---------------------------------------------------------------------------
__global__ __launch_bounds__(256) void sim_argmax_kernel(
        const float* __restrict__ x,
        const float* __restrict__ pnT,
        int* __restrict__ out) {
    __shared__ float xt[C * MT];    // 24 KB, [c][pos]; reused for candidates
    __shared__ float pt[C * NT];    // 24 KB, [c][proto]
    __shared__ float n2s[MT];

    int tid = threadIdx.x;
    int m0 = blockIdx.x * MT;
    int b = (m0 >= P_PER_B) ? 1 : 0;
    int p0 = m0 - b * P_PER_B;
    const float* xb = x + (size_t)b * (size_t)C * P_PER_B + p0;

    int co = tid >> 4;   // 0..15
    int q = tid & 15;    // 0..15

    // stage x tile: 6 iters x (16 rows x 16 float4) — coalesced
#pragma unroll
    for (int i = 0; i < 6; ++i) {
        int c = i * 16 + co;
        float4 v = *(const float4*)(xb + (size_t)c * P_PER_B + q * 4);
        *(float4*)(xt + c * MT + q * 4) = v;
    }
    __syncthreads();

    // per-position ||x||^2 (threads 0..63; consecutive-word LDS reads)
    if (tid < MT) {
        float s = 0.f;
        for (int c = 0; c < C; ++c) {
            float v = xt[c * MT + tid];
            s = fmaf(v, v, s);
        }
        n2s[tid] = s;
    }

    int tm = tid & 15;   // position group: positions tm*4 .. tm*4+3
    int tn = tid >> 4;   // proto group:    protos   tn*4 .. tn*4+3 (per chunk)

    float best[4], second[4];
    int bestk[4];
#pragma unroll
    for (int i = 0; i < 4; ++i) {
        best[i] = -3.4e38f;
        second[i] = -3.4e38f;
        bestk[i] = 0;
    }

#pragma unroll 1
    for (int n0 = 0; n0 < K; n0 += NT) {
        __syncthreads();   // protect pt from previous chunk's readers
#pragma unroll
        for (int i = 0; i < 6; ++i) {
            int c = i * 16 + co;
            float4 v = *(const float4*)(pnT + (size_t)c * K + n0 + q * 4);
            *(float4*)(pt + c * NT + q * 4) = v;
        }
        __syncthreads();

        float acc[4][4];
#pragma unroll
        for (int i = 0; i < 4; ++i)
#pragma unroll
            for (int j = 0; j < 4; ++j) acc[i][j] = 0.f;

#pragma unroll 4
        for (int c = 0; c < C; ++c) {
            float4 xv = *(const float4*)(xt + c * MT + tm * 4);
            float4 pv = *(const float4*)(pt + c * NT + tn * 4);
            acc[0][0] = fmaf(xv.x, pv.x, acc[0][0]);
            acc[0][1] = fmaf(xv.x, pv.y, acc[0][1]);
            acc[0][2] = fmaf(xv.x, pv.z, acc[0][2]);
            acc[0][3] = fmaf(xv.x, pv.w, acc[0][3]);
            acc[1][0] = fmaf(xv.y, pv.x, acc[1][0]);
            acc[1][1] = fmaf(xv.y, pv.y, acc[1][1]);
            acc[1][2] = fmaf(xv.y, pv.z, acc[1][2]);
            acc[1][3] = fmaf(xv.y, pv.w, acc[1][3]);
            acc[2][0] = fmaf(xv.z, pv.x, acc[2][0]);
            acc[2][1] = fmaf(xv.z, pv.y, acc[2][1]);
            acc[2][2] = fmaf(xv.z, pv.z, acc[2][2]);
            acc[2][3] = fmaf(xv.z, pv.w, acc[2][3]);
            acc[3][0] = fmaf(xv.w, pv.x, acc[3][0]);
            acc[3][1] = fmaf(xv.w, pv.y, acc[3][1]);
            acc[3][2] = fmaf(xv.w, pv.z, acc[3][2]);
            acc[3][3] = fmaf(xv.w, pv.w, acc[3][3]);
        }

#pragma unroll
        for (int i = 0; i < 4; ++i) {
#pragma unroll
            for (int j = 0; j < 4; ++j) {
                float s = acc[i][j];
                int k = n0 + tn * 4 + j;
                if (s > best[i]) {
                    second[i] = best[i];
                    best[i] = s;
                    bestk[i] = k;
                } else if (s > second[i]) {
                    second[i] = s;
                }
            }
        }
    }

    // -------- per-position merge across the 16 tn threads (reuse xt) -------
    __syncthreads();                    // last chunk's xt/pt reads done
    float* cb = xt;                     // [64][16] best
    float* cs = xt + MT * 16;           // [64][16] second
    int* ck = (int*)(xt + 2 * MT * 16); // [64][16] bestk
#pragma unroll
    for (int i = 0; i < 4; ++i) {
        int pos = tm * 4 + i;
        cb[pos * 16 + tn] = best[i];
        cs[pos * 16 + tn] = second[i];
        ck[pos * 16 + tn] = bestk[i];
    }
    __syncthreads();

    if (tid < MT) {
        float b_ = cb[tid * 16];
        float s_ = cs[tid * 16];
        int k_ = ck[tid * 16];
        for (int j = 1; j < 16; ++j) {
            float nb = cb[tid * 16 + j];
            float ns = cs[tid * 16 + j];
            int nk = ck[tid * 16 + j];
            if (nb > b_) {              // disjoint sets: new 2nd = max(old best, its 2nd)
                s_ = fmaxf(b_, ns);
                b_ = nb;
                k_ = nk;
            } else {
                s_ = fmaxf(s_, nb);     // nb==b_ -> s_=b_ -> margin 0 -> flagged
                if (nb == b_ && nk < k_) k_ = nk;
            }
        }
        // worst-case (fast-pass + numpy) rounding < 1.8e-5*||x||; 5x margin.
        float tau = 1e-4f * sqrtf(n2s[tid]);
        out[m0 + tid] = (b_ - s_ < tau) ? (k_ | (int)0x80000000) : k_;
    }
}

// ---------------------------------------------------------------------------
// Refine pass (validated round 3): bit-exact numpy-fp32 emulation of flagged
// positions. Thread t handles prototypes t and t+256 (reads pnT channel-
// major — same stored bits, same c-ascending order). LDS tree argmax with
// first-index tie-break.
// ---------------------------------------------------------------------------
__global__ __launch_bounds__(256) void refine_kernel(
        const float* __restrict__ x,
        const float* __restrict__ pnT,
        int* __restrict__ out) {
    __shared__ int list[256];
    __shared__ int cnt;
    __shared__ float xn[C];
    __shared__ float nrm_s;
    __shared__ float sc[256];
    __shared__ int ki[256];

    int tid = threadIdx.x;
    int g = blockIdx.x * 256 + tid;

    if (tid == 0) cnt = 0;
    __syncthreads();

    if (out[g] < 0) {
        int i = atomicAdd(&cnt, 1);
        list[i] = g;
    }
    __syncthreads();
    int n = cnt;

    for (int i = 0; i < n; ++i) {
        int gg = list[i];
        int b = (gg >= P_PER_B) ? 1 : 0;
        int p = gg - b * P_PER_B;
        const float* xb = x + (size_t)b * (size_t)C * P_PER_B + p;

        if (tid < C) xn[tid] = xb[(size_t)tid * P_PER_B];
        __syncthreads();

        // numpy: norm over non-contiguous axis -> strictly sequential fp32
        if (tid == 0) {
            float acc = __fmul_rn(xn[0], xn[0]);
            for (int c = 1; c < C; ++c)
                acc = __fadd_rn(acc, __fmul_rn(xn[c], xn[c]));
            nrm_s = fmaxf(__fsqrt_rn(acc), 1e-12f);
        }
        __syncthreads();
        if (tid < C) xn[tid] = __fdiv_rn(xn[tid], nrm_s);
        __syncthreads();

        // einsum optimize=False: sequential fp32 mul+add, c ascending, no FMA
        float s0 = 0.f, s1 = 0.f;
        for (int c = 0; c < C; ++c) {
            s0 = __fadd_rn(s0, __fmul_rn(xn[c], pnT[(size_t)c * K + tid]));
            s1 = __fadd_rn(s1, __fmul_rn(xn[c], pnT[(size_t)c * K + tid + 256]));
        }

        float bv = s0;
        int bk = tid;
        if (s1 > bv) { bv = s1; bk = tid + 256; }  // strict: lower index wins ties

        sc[tid] = bv;
        ki[tid] = bk;
        __syncthreads();

        for (int off = 128; off > 0; off >>= 1) {
            if (tid < off) {
                float ov = sc[tid + off];
                int oi = ki[tid + off];
                if (ov > sc[tid] || (ov == sc[tid] && oi < ki[tid])) {
                    sc[tid] = ov;
                    ki[tid] = oi;
                }
            }
            __syncthreads();
        }

        if (tid == 0) out[gg] = ki[0];
        __syncthreads();
    }
}

// ---------------------------------------------------------------------------
extern "C" void kernel_launch(void* const* d_in, const int* in_sizes, int n_in,
                              void* d_out, int out_size, void* d_ws, size_t ws_size,
                              hipStream_t stream) {
    const float* x = (const float*)d_in[0];      // [2,96,48,48,48] fp32
    const float* proto = (const float*)d_in[1];  // [512,96] fp32
    int* out = (int*)d_out;                      // [2,48,48,48] int32

    float* pnT = (float*)d_ws;                   // 96*512*4 = 196608 B

    prep_kernel<<<2, 256, 0, stream>>>(proto, pnT);
    sim_argmax_kernel<<<NPOS / MT, 256, 0, stream>>>(x, pnT, out);
    refine_kernel<<<NPOS / 256, 256, 0, stream>>>(x, pnT, out);
}